// Round 1
// baseline (7645.985 us; speedup 1.0000x reference)
//
#include <hip/hip_runtime.h>
#include <hip/hip_bf16.h>
#include <math.h>

// Problem constants
#define HH 320
#define WW 320
#define NP (HH*WW)        // 102400
#define CC 32
#define DD 32

#define H2 160
#define W2 160
#define N2 (H2*W2)        // 25600
#define H4 80
#define W4 80
#define N4 (H4*W4)        // 6400
#define H8 40
#define W8 40
#define N8 (H8*W8)        // 1600

// ---------------- workspace layout (float offsets) ----------------
#define OFF_REL   0            // 24 floats used (2 views x (rot9 + trans3)), pad to 64
#define OFF_S1A   64
#define OFF_S2A   (OFF_S1A + 8*NP)     // 819264
#define OFF_S3A   (OFF_S2A + 16*N2)    // 1228864
#define OFF_S4A   (OFF_S3A + 32*N4)    // 1433664
#define OFF_ESUM  (OFF_S4A + 64*N8)    // 1536064
#define OFF_DIMG  (OFF_ESUM + NP)      // 1638464
#define OFF_MAXP  (OFF_DIMG + NP)      // 1740864
#define OFF_ZEND  (OFF_MAXP + NP)      // 1843264
#define OFF_S1B   OFF_ZEND
#define OFF_S2B   (OFF_S1B + 8*NP)
#define OFF_S3B   (OFF_S2B + 16*N2)
#define OFF_S4B   (OFF_S3B + 32*N4)
#define OFF_VAR   (OFF_S4B + 64*N8)    // 3379264, size CC*NP
// u-buffers alias the var region (var dead after conv_a)
#define OFF_U3    OFF_VAR
#define OFF_U2    (OFF_U3 + 32*N4)
#define OFF_U1    (OFF_U2 + 16*N2)
#define OFF_END   (OFF_VAR + CC*NP)    // 6656064 floats = ~25.4 MB

// ---------------- prep: rel = proj[v] @ inv(proj[0]), v=1,2 ----------------
__global__ void k_prep(const float* __restrict__ proj, float* __restrict__ rel) {
    if (threadIdx.x != 0 || blockIdx.x != 0) return;
    double a[4][8];
    for (int i = 0; i < 4; i++)
        for (int j = 0; j < 4; j++) {
            a[i][j] = (double)proj[i*4 + j];
            a[i][j+4] = (i == j) ? 1.0 : 0.0;
        }
    for (int c = 0; c < 4; c++) {
        int pv = c; double best = fabs(a[c][c]);
        for (int r = c+1; r < 4; r++) {
            double v = fabs(a[r][c]);
            if (v > best) { best = v; pv = r; }
        }
        if (pv != c)
            for (int j = 0; j < 8; j++) { double t = a[c][j]; a[c][j] = a[pv][j]; a[pv][j] = t; }
        double inv = 1.0 / a[c][c];
        for (int j = 0; j < 8; j++) a[c][j] *= inv;
        for (int r = 0; r < 4; r++) if (r != c) {
            double f = a[r][c];
            for (int j = 0; j < 8; j++) a[r][j] -= f * a[c][j];
        }
    }
    for (int v = 1; v < 3; v++) {
        const float* P = proj + v*16;
        double rm[4][4];
        for (int i = 0; i < 4; i++)
            for (int j = 0; j < 4; j++) {
                double s = 0.0;
                for (int k = 0; k < 4; k++) s += (double)P[i*4 + k] * a[k][j+4];
                rm[i][j] = s;
            }
        float* o = rel + (v-1)*12;
        o[0]=(float)rm[0][0]; o[1]=(float)rm[0][1]; o[2]=(float)rm[0][2];
        o[3]=(float)rm[1][0]; o[4]=(float)rm[1][1]; o[5]=(float)rm[1][2];
        o[6]=(float)rm[2][0]; o[7]=(float)rm[2][1]; o[8]=(float)rm[2][2];
        o[9]=(float)rm[0][3]; o[10]=(float)rm[1][3]; o[11]=(float)rm[2][3];
    }
}

// ---------------- warp + variance ----------------
__global__ __launch_bounds__(256) void k_warp_var(
        const float* __restrict__ feats, const float* __restrict__ rel,
        const float* __restrict__ dslice, float* __restrict__ var) {
    int p = blockIdx.x*256 + threadIdx.x;
    if (p >= NP) return;
    int y = p / WW, x = p - y*WW;
    float fx = (float)x, fy = (float)y;
    float depth = dslice[p];
    int offs[8]; float wts[8];
#pragma unroll
    for (int v = 0; v < 2; v++) {
        const float* r = rel + v*12;
        float X = (r[0]*fx + r[1]*fy + r[2]) * depth + r[9];
        float Y = (r[3]*fx + r[4]*fy + r[5]) * depth + r[10];
        float Z = (r[6]*fx + r[7]*fy + r[8]) * depth + r[11];
        float iz = 1.0f / Z;
        float px = X * iz, py = Y * iz;
        float x0f = floorf(px), y0f = floorf(py);
        float wx = px - x0f, wy = py - y0f;
        int x0 = (int)x0f, y0 = (int)y0f;
#pragma unroll
        for (int t = 0; t < 4; t++) {
            int xi = x0 + (t & 1), yi = y0 + (t >> 1);
            float wgt = ((t & 1) ? wx : 1.0f - wx) * ((t >> 1) ? wy : 1.0f - wy);
            bool valid = (xi >= 0) && (xi <= WW-1) && (yi >= 0) && (yi <= HH-1);
            int xc = min(max(xi, 0), WW-1);
            int yc = min(max(yi, 0), HH-1);
            offs[v*4 + t] = yc*WW + xc;
            wts[v*4 + t] = valid ? wgt : 0.0f;
        }
    }
    const float* f0 = feats;
    const float* f1 = feats + CC*NP;
    const float* f2 = feats + 2*CC*NP;
    const float inv3 = 1.0f / 3.0f;
#pragma unroll 4
    for (int c = 0; c < CC; c++) {
        float rv = f0[c*NP + p];
        float sum = rv, sq = rv * rv;
        const float* b1 = f1 + c*NP;
        float t1 = b1[offs[0]]*wts[0] + b1[offs[1]]*wts[1] + b1[offs[2]]*wts[2] + b1[offs[3]]*wts[3];
        const float* b2 = f2 + c*NP;
        float t2 = b2[offs[4]]*wts[4] + b2[offs[5]]*wts[5] + b2[offs[6]]*wts[6] + b2[offs[7]]*wts[7];
        sum += t1 + t2;
        sq  += t1*t1 + t2*t2;
        float m = sum * inv3;
        var[c*NP + p] = sq * inv3 - m*m;
    }
}

// ---------------- conv stage 1: c1 = relu(conv3x3(var,W0) + conv3x3(s1,Ws1)), 8ch @ 320^2 ----
__global__ __launch_bounds__(256) void k_conv_a(
        const float* __restrict__ var, const float* __restrict__ s1,
        const float* __restrict__ W0, const float* __restrict__ Ws1,
        float* __restrict__ c1) {
    int p = blockIdx.x*256 + threadIdx.x;
    if (p >= NP) return;
    int y = p / WW, x = p - y*WW;
    int offs[9]; float msk[9];
#pragma unroll
    for (int k = 0; k < 9; k++) {
        int yy = y + k/3 - 1, xx = x + k%3 - 1;
        bool v = (yy >= 0) && (yy < HH) && (xx >= 0) && (xx < WW);
        offs[k] = v ? yy*WW + xx : 0;
        msk[k] = v ? 1.0f : 0.0f;
    }
    float acc[8];
#pragma unroll
    for (int o = 0; o < 8; o++) acc[o] = 0.0f;
    for (int ci = 0; ci < 32; ci++) {
        const float* b = var + ci*NP;
        float t[9];
#pragma unroll
        for (int k = 0; k < 9; k++) t[k] = b[offs[k]] * msk[k];
#pragma unroll
        for (int o = 0; o < 8; o++) {
            const float* w = W0 + (o*32 + ci)*9;
            float a = acc[o];
#pragma unroll
            for (int k = 0; k < 9; k++) a += t[k] * w[k];
            acc[o] = a;
        }
    }
    for (int ci = 0; ci < 8; ci++) {
        const float* b = s1 + ci*NP;
        float t[9];
#pragma unroll
        for (int k = 0; k < 9; k++) t[k] = b[offs[k]] * msk[k];
#pragma unroll
        for (int o = 0; o < 8; o++) {
            const float* w = Ws1 + (o*8 + ci)*9;
            float a = acc[o];
#pragma unroll
            for (int k = 0; k < 9; k++) a += t[k] * w[k];
            acc[o] = a;
        }
    }
#pragma unroll
    for (int o = 0; o < 8; o++) c1[o*NP + p] = fmaxf(acc[o], 0.0f);
}

// ---------------- conv stage 2: c2 = relu(conv3x3s2(c1,W1) + conv3x3(s2,Ws2)), 16ch @ 160^2 ----
__global__ __launch_bounds__(256) void k_conv_b(
        const float* __restrict__ c1, const float* __restrict__ s2,
        const float* __restrict__ W1, const float* __restrict__ Ws2,
        float* __restrict__ c2) {
    int p = blockIdx.x*256 + threadIdx.x;
    if (p >= N2) return;
    int og = blockIdx.y;              // output-channel group (8 each)
    int y = p / W2, x = p - y*W2;
    // strided taps on 320^2 input: rows 2y+k, pad (0,1)
    int offsA[9]; float mskA[9];
#pragma unroll
    for (int k = 0; k < 9; k++) {
        int yy = 2*y + k/3, xx = 2*x + k%3;
        bool v = (yy < HH) && (xx < WW);
        offsA[k] = v ? yy*WW + xx : 0;
        mskA[k] = v ? 1.0f : 0.0f;
    }
    // skip taps on 160^2, pad 1
    int offsB[9]; float mskB[9];
#pragma unroll
    for (int k = 0; k < 9; k++) {
        int yy = y + k/3 - 1, xx = x + k%3 - 1;
        bool v = (yy >= 0) && (yy < H2) && (xx >= 0) && (xx < W2);
        offsB[k] = v ? yy*W2 + xx : 0;
        mskB[k] = v ? 1.0f : 0.0f;
    }
    float acc[8];
#pragma unroll
    for (int o = 0; o < 8; o++) acc[o] = 0.0f;
    for (int ci = 0; ci < 8; ci++) {
        const float* b = c1 + ci*NP;
        float t[9];
#pragma unroll
        for (int k = 0; k < 9; k++) t[k] = b[offsA[k]] * mskA[k];
#pragma unroll
        for (int o = 0; o < 8; o++) {
            const float* w = W1 + ((og*8 + o)*8 + ci)*9;
            float a = acc[o];
#pragma unroll
            for (int k = 0; k < 9; k++) a += t[k] * w[k];
            acc[o] = a;
        }
    }
    for (int ci = 0; ci < 16; ci++) {
        const float* b = s2 + ci*N2;
        float t[9];
#pragma unroll
        for (int k = 0; k < 9; k++) t[k] = b[offsB[k]] * mskB[k];
#pragma unroll
        for (int o = 0; o < 8; o++) {
            const float* w = Ws2 + ((og*8 + o)*16 + ci)*9;
            float a = acc[o];
#pragma unroll
            for (int k = 0; k < 9; k++) a += t[k] * w[k];
            acc[o] = a;
        }
    }
#pragma unroll
    for (int o = 0; o < 8; o++) c2[(og*8 + o)*N2 + p] = fmaxf(acc[o], 0.0f);
}

// ---------------- conv stage 3: c3 = relu(conv3x3s2(c2,W2) + conv3x3(s3,Ws3)), 32ch @ 80^2 ----
__global__ __launch_bounds__(256) void k_conv_c(
        const float* __restrict__ c2, const float* __restrict__ s3,
        const float* __restrict__ W2w, const float* __restrict__ Ws3,
        float* __restrict__ c3) {
    int p = blockIdx.x*256 + threadIdx.x;
    if (p >= N4) return;
    int og = blockIdx.y;
    int y = p / W4, x = p - y*W4;
    int offsA[9]; float mskA[9];
#pragma unroll
    for (int k = 0; k < 9; k++) {
        int yy = 2*y + k/3, xx = 2*x + k%3;
        bool v = (yy < H2) && (xx < W2);
        offsA[k] = v ? yy*W2 + xx : 0;
        mskA[k] = v ? 1.0f : 0.0f;
    }
    int offsB[9]; float mskB[9];
#pragma unroll
    for (int k = 0; k < 9; k++) {
        int yy = y + k/3 - 1, xx = x + k%3 - 1;
        bool v = (yy >= 0) && (yy < H4) && (xx >= 0) && (xx < W4);
        offsB[k] = v ? yy*W4 + xx : 0;
        mskB[k] = v ? 1.0f : 0.0f;
    }
    float acc[8];
#pragma unroll
    for (int o = 0; o < 8; o++) acc[o] = 0.0f;
    for (int ci = 0; ci < 16; ci++) {
        const float* b = c2 + ci*N2;
        float t[9];
#pragma unroll
        for (int k = 0; k < 9; k++) t[k] = b[offsA[k]] * mskA[k];
#pragma unroll
        for (int o = 0; o < 8; o++) {
            const float* w = W2w + ((og*8 + o)*16 + ci)*9;
            float a = acc[o];
#pragma unroll
            for (int k = 0; k < 9; k++) a += t[k] * w[k];
            acc[o] = a;
        }
    }
    for (int ci = 0; ci < 32; ci++) {
        const float* b = s3 + ci*N4;
        float t[9];
#pragma unroll
        for (int k = 0; k < 9; k++) t[k] = b[offsB[k]] * mskB[k];
#pragma unroll
        for (int o = 0; o < 8; o++) {
            const float* w = Ws3 + ((og*8 + o)*32 + ci)*9;
            float a = acc[o];
#pragma unroll
            for (int k = 0; k < 9; k++) a += t[k] * w[k];
            acc[o] = a;
        }
    }
#pragma unroll
    for (int o = 0; o < 8; o++) c3[(og*8 + o)*N4 + p] = fmaxf(acc[o], 0.0f);
}

// ---------------- conv stage 4: c4 = relu(conv3x3s2(c3,W3) + conv3x3(s4,Ws4)), 64ch @ 40^2 ----
__global__ __launch_bounds__(256) void k_conv_d(
        const float* __restrict__ c3, const float* __restrict__ s4,
        const float* __restrict__ W3w, const float* __restrict__ Ws4,
        float* __restrict__ c4) {
    int p = blockIdx.x*256 + threadIdx.x;
    if (p >= N8) return;
    int og = blockIdx.y;              // 8 groups of 8
    int y = p / W8, x = p - y*W8;
    int offsA[9]; float mskA[9];
#pragma unroll
    for (int k = 0; k < 9; k++) {
        int yy = 2*y + k/3, xx = 2*x + k%3;
        bool v = (yy < H4) && (xx < W4);
        offsA[k] = v ? yy*W4 + xx : 0;
        mskA[k] = v ? 1.0f : 0.0f;
    }
    int offsB[9]; float mskB[9];
#pragma unroll
    for (int k = 0; k < 9; k++) {
        int yy = y + k/3 - 1, xx = x + k%3 - 1;
        bool v = (yy >= 0) && (yy < H8) && (xx >= 0) && (xx < W8);
        offsB[k] = v ? yy*W8 + xx : 0;
        mskB[k] = v ? 1.0f : 0.0f;
    }
    float acc[8];
#pragma unroll
    for (int o = 0; o < 8; o++) acc[o] = 0.0f;
    for (int ci = 0; ci < 32; ci++) {
        const float* b = c3 + ci*N4;
        float t[9];
#pragma unroll
        for (int k = 0; k < 9; k++) t[k] = b[offsA[k]] * mskA[k];
#pragma unroll
        for (int o = 0; o < 8; o++) {
            const float* w = W3w + ((og*8 + o)*32 + ci)*9;
            float a = acc[o];
#pragma unroll
            for (int k = 0; k < 9; k++) a += t[k] * w[k];
            acc[o] = a;
        }
    }
    for (int ci = 0; ci < 64; ci++) {
        const float* b = s4 + ci*N8;
        float t[9];
#pragma unroll
        for (int k = 0; k < 9; k++) t[k] = b[offsB[k]] * mskB[k];
#pragma unroll
        for (int o = 0; o < 8; o++) {
            const float* w = Ws4 + ((og*8 + o)*64 + ci)*9;
            float a = acc[o];
#pragma unroll
            for (int k = 0; k < 9; k++) a += t[k] * w[k];
            acc[o] = a;
        }
    }
#pragma unroll
    for (int o = 0; o < 8; o++) c4[(og*8 + o)*N8 + p] = fmaxf(acc[o], 0.0f);
}

// ---------------- u3 = c3 + up2(conv1x1(c4, U4)) : 32ch @ 80^2 ----------------
__global__ __launch_bounds__(256) void k_up4(
        const float* __restrict__ c4, const float* __restrict__ c3,
        const float* __restrict__ U4, float* __restrict__ u3) {
    int idx = blockIdx.x*256 + threadIdx.x;
    if (idx >= 32*N4) return;
    int co = idx / N4; int p = idx - co*N4;
    int y = p / W4, x = p - y*W4;
    int pl = (y >> 1)*W8 + (x >> 1);
    const float* w = U4 + co*64;
    float s = 0.0f;
#pragma unroll 8
    for (int ci = 0; ci < 64; ci++) s += c4[ci*N8 + pl] * w[ci];
    u3[idx] = c3[idx] + s;
}

// ---------------- u2 = c2 + up2(conv1x1(u3, U3)) : 16ch @ 160^2 ----------------
__global__ __launch_bounds__(256) void k_up3(
        const float* __restrict__ u3, const float* __restrict__ c2,
        const float* __restrict__ U3, float* __restrict__ u2) {
    int idx = blockIdx.x*256 + threadIdx.x;
    if (idx >= 16*N2) return;
    int co = idx / N2; int p = idx - co*N2;
    int y = p / W2, x = p - y*W2;
    int pl = (y >> 1)*W4 + (x >> 1);
    const float* w = U3 + co*32;
    float s = 0.0f;
#pragma unroll 8
    for (int ci = 0; ci < 32; ci++) s += u3[ci*N4 + pl] * w[ci];
    u2[idx] = c2[idx] + s;
}

// ---------------- u1 = c1 + up2(conv1x1(u2, U2)) : 8ch @ 320^2 ----------------
__global__ __launch_bounds__(256) void k_up2(
        const float* __restrict__ u2, const float* __restrict__ c1,
        const float* __restrict__ U2, float* __restrict__ u1) {
    int idx = blockIdx.x*256 + threadIdx.x;
    if (idx >= 8*NP) return;
    int co = idx / NP; int p = idx - co*NP;
    int y = p / WW, x = p - y*WW;
    int pl = (y >> 1)*W2 + (x >> 1);
    const float* w = U2 + co*16;
    float s = 0.0f;
#pragma unroll
    for (int ci = 0; ci < 16; ci++) s += u2[ci*N2 + pl] * w[ci];
    u1[idx] = c1[idx] + s;
}

// ---------------- cost conv (1ch 3x3) + prob accumulation ----------------
__global__ __launch_bounds__(256) void k_cost(
        const float* __restrict__ u1, const float* __restrict__ Wout,
        const float* __restrict__ dslice,
        float* __restrict__ exp_sum, float* __restrict__ depth_img,
        float* __restrict__ max_prob) {
    int p = blockIdx.x*256 + threadIdx.x;
    if (p >= NP) return;
    int y = p / WW, x = p - y*WW;
    int offs[9]; float msk[9];
#pragma unroll
    for (int k = 0; k < 9; k++) {
        int yy = y + k/3 - 1, xx = x + k%3 - 1;
        bool v = (yy >= 0) && (yy < HH) && (xx >= 0) && (xx < WW);
        offs[k] = v ? yy*WW + xx : 0;
        msk[k] = v ? 1.0f : 0.0f;
    }
    float cost = 0.0f;
#pragma unroll
    for (int ci = 0; ci < 8; ci++) {
        const float* b = u1 + ci*NP;
        const float* w = Wout + ci*9;
#pragma unroll
        for (int k = 0; k < 9; k++) cost += b[offs[k]] * msk[k] * w[k];
    }
    float prob = expf(cost);
    exp_sum[p] += prob;
    depth_img[p] += dslice[p] * prob;
    max_prob[p] = fmaxf(max_prob[p], prob);
}

// ---------------- final normalize ----------------
__global__ __launch_bounds__(256) void k_final(
        const float* __restrict__ exp_sum, const float* __restrict__ depth_img,
        const float* __restrict__ max_prob, float* __restrict__ out) {
    int p = blockIdx.x*256 + threadIdx.x;
    if (p >= NP) return;
    float es = exp_sum[p] + 1e-10f;
    out[p] = depth_img[p] / es;
    out[NP + p] = max_prob[p] / es;
}

extern "C" void kernel_launch(void* const* d_in, const int* in_sizes, int n_in,
                              void* d_out, int out_size, void* d_ws, size_t ws_size,
                              hipStream_t stream) {
    const float* feats = (const float*)d_in[0];
    const float* proj  = (const float*)d_in[1];
    const float* depthv= (const float*)d_in[2];
    const float* W0  = (const float*)d_in[3];
    const float* Ws1 = (const float*)d_in[4];
    const float* W1  = (const float*)d_in[5];
    const float* Ws2 = (const float*)d_in[6];
    const float* W2w = (const float*)d_in[7];
    const float* Ws3 = (const float*)d_in[8];
    const float* W3w = (const float*)d_in[9];
    const float* Ws4 = (const float*)d_in[10];
    const float* U4  = (const float*)d_in[11];
    const float* U3  = (const float*)d_in[12];
    const float* U2  = (const float*)d_in[13];
    const float* Wout= (const float*)d_in[14];

    float* ws = (float*)d_ws;
    float* rel  = ws + OFF_REL;
    float* s1a  = ws + OFF_S1A;
    float* s2a  = ws + OFF_S2A;
    float* s3a  = ws + OFF_S3A;
    float* s4a  = ws + OFF_S4A;
    float* esum = ws + OFF_ESUM;
    float* dimg = ws + OFF_DIMG;
    float* maxp = ws + OFF_MAXP;
    float* s1b  = ws + OFF_S1B;
    float* s2b  = ws + OFF_S2B;
    float* s3b  = ws + OFF_S3B;
    float* s4b  = ws + OFF_S4B;
    float* var  = ws + OFF_VAR;
    float* u3   = ws + OFF_U3;
    float* u2   = ws + OFF_U2;
    float* u1   = ws + OFF_U1;

    // zero: skip set A + accumulators (ws is poisoned 0xAA before every call)
    hipMemsetAsync(ws + OFF_S1A, 0, (size_t)(OFF_ZEND - OFF_S1A) * sizeof(float), stream);
    k_prep<<<1, 1, 0, stream>>>(proj, rel);

    for (int d = 0; d < DD; d++) {
        const float* dsl = depthv + (size_t)d * NP;
        // ping-pong skips: even d reads A writes B; odd d reads B writes A
        float *rs1, *rs2, *rs3, *rs4, *wc1, *wc2, *wc3, *wc4;
        if ((d & 1) == 0) {
            rs1=s1a; rs2=s2a; rs3=s3a; rs4=s4a;
            wc1=s1b; wc2=s2b; wc3=s3b; wc4=s4b;
        } else {
            rs1=s1b; rs2=s2b; rs3=s3b; rs4=s4b;
            wc1=s1a; wc2=s2a; wc3=s3a; wc4=s4a;
        }
        k_warp_var<<<dim3(400), 256, 0, stream>>>(feats, rel, dsl, var);
        k_conv_a<<<dim3(400), 256, 0, stream>>>(var, rs1, W0, Ws1, wc1);
        k_conv_b<<<dim3(100, 2), 256, 0, stream>>>(wc1, rs2, W1, Ws2, wc2);
        k_conv_c<<<dim3(25, 4), 256, 0, stream>>>(wc2, rs3, W2w, Ws3, wc3);
        k_conv_d<<<dim3(7, 8), 256, 0, stream>>>(wc3, rs4, W3w, Ws4, wc4);
        k_up4<<<dim3(800), 256, 0, stream>>>(wc4, wc3, U4, u3);
        k_up3<<<dim3(1600), 256, 0, stream>>>(u3, wc2, U3, u2);
        k_up2<<<dim3(3200), 256, 0, stream>>>(u2, wc1, U2, u1);
        k_cost<<<dim3(400), 256, 0, stream>>>(u1, Wout, dsl, esum, dimg, maxp);
    }
    k_final<<<dim3(400), 256, 0, stream>>>(esum, dimg, maxp, (float*)d_out);
}

// Round 2
// 5519.007 us; speedup vs baseline: 1.3854x; 1.3854x over previous
//
#include <hip/hip_runtime.h>
#include <hip/hip_bf16.h>
#include <math.h>

// Problem constants
#define HH 320
#define WW 320
#define NP (HH*WW)        // 102400
#define CC 32
#define DD 32

#define H2 160
#define W2 160
#define N2 (H2*W2)        // 25600
#define H4 80
#define W4 80
#define N4 (H4*W4)        // 6400
#define H8 40
#define W8 40
#define N8 (H8*W8)        // 1600

#define HALO 18
#define NHALO (HALO*HALO) // 324

// ---------------- workspace layout (float offsets) ----------------
#define OFF_REL   0                    // 24 floats used, pad to 64
#define OFF_S1A   64
#define OFF_S2A   (OFF_S1A + 8*NP)
#define OFF_S3A   (OFF_S2A + 16*N2)
#define OFF_S4A   (OFF_S3A + 32*N4)
#define OFF_ESUM  (OFF_S4A + 64*N8)
#define OFF_DIMG  (OFF_ESUM + NP)
#define OFF_MAXP  (OFF_DIMG + NP)
#define OFF_ZEND  (OFF_MAXP + NP)      // everything below here is zero-initialized
#define OFF_S1B   OFF_ZEND
#define OFF_S2B   (OFF_S1B + 8*NP)
#define OFF_S3B   (OFF_S2B + 16*N2)
#define OFF_S4B   (OFF_S3B + 32*N4)
#define OFF_END   (OFF_S4B + 64*N8)    // ~3.7M floats = ~14.7 MB

// ---------------- prep: rel = proj[v] @ inv(proj[0]), v=1,2 ----------------
__global__ void k_prep(const float* __restrict__ proj, float* __restrict__ rel) {
    if (threadIdx.x != 0 || blockIdx.x != 0) return;
    double a[4][8];
    for (int i = 0; i < 4; i++)
        for (int j = 0; j < 4; j++) {
            a[i][j] = (double)proj[i*4 + j];
            a[i][j+4] = (i == j) ? 1.0 : 0.0;
        }
    for (int c = 0; c < 4; c++) {
        int pv = c; double best = fabs(a[c][c]);
        for (int r = c+1; r < 4; r++) {
            double v = fabs(a[r][c]);
            if (v > best) { best = v; pv = r; }
        }
        if (pv != c)
            for (int j = 0; j < 8; j++) { double t = a[c][j]; a[c][j] = a[pv][j]; a[pv][j] = t; }
        double inv = 1.0 / a[c][c];
        for (int j = 0; j < 8; j++) a[c][j] *= inv;
        for (int r = 0; r < 4; r++) if (r != c) {
            double f = a[r][c];
            for (int j = 0; j < 8; j++) a[r][j] -= f * a[c][j];
        }
    }
    for (int v = 1; v < 3; v++) {
        const float* P = proj + v*16;
        double rm[4][4];
        for (int i = 0; i < 4; i++)
            for (int j = 0; j < 4; j++) {
                double s = 0.0;
                for (int k = 0; k < 4; k++) s += (double)P[i*4 + k] * a[k][j+4];
                rm[i][j] = s;
            }
        float* o = rel + (v-1)*12;
        o[0]=(float)rm[0][0]; o[1]=(float)rm[0][1]; o[2]=(float)rm[0][2];
        o[3]=(float)rm[1][0]; o[4]=(float)rm[1][1]; o[5]=(float)rm[1][2];
        o[6]=(float)rm[2][0]; o[7]=(float)rm[2][1]; o[8]=(float)rm[2][2];
        o[9]=(float)rm[0][3]; o[10]=(float)rm[1][3]; o[11]=(float)rm[2][3];
    }
}

// ---- fused warp+variance+conv_a: c1 = relu(conv3x3(var,W0) + conv3x3(s1,Ws1)) ----
// one block per 16x16 output tile; var computed into zero-padded 18x18 LDS halo
__global__ __launch_bounds__(256) void k_warp_conv_a(
        const float* __restrict__ feats, const float* __restrict__ rel,
        const float* __restrict__ dslice, const float* __restrict__ s1,
        const float* __restrict__ W0, const float* __restrict__ Ws1,
        float* __restrict__ c1out) {
    __shared__ float vs[32][NHALO];   // 41472 B
    __shared__ float ss[8][NHALO];    // 10368 B
    int bx = blockIdx.x % 20, by = blockIdx.x / 20;
    int ox0 = bx*16, oy0 = by*16;

    const float* f0 = feats;
    const float* f1 = feats + CC*NP;
    const float* f2 = feats + 2*CC*NP;
    const float inv3 = 1.0f / 3.0f;

    for (int hp = threadIdx.x; hp < NHALO; hp += 256) {
        int hy = hp / HALO, hx = hp - hy*HALO;
        int gy = oy0 + hy - 1, gx = ox0 + hx - 1;
        if (gy < 0 || gy >= HH || gx < 0 || gx >= WW) {
#pragma unroll
            for (int c = 0; c < 32; c++) vs[c][hp] = 0.0f;
#pragma unroll
            for (int c = 0; c < 8; c++) ss[c][hp] = 0.0f;
        } else {
            int p = gy*WW + gx;
            float depth = dslice[p];
            float fx = (float)gx, fy = (float)gy;
            int offs[8]; float wts[8];
#pragma unroll
            for (int v = 0; v < 2; v++) {
                const float* r = rel + v*12;
                float X = (r[0]*fx + r[1]*fy + r[2]) * depth + r[9];
                float Y = (r[3]*fx + r[4]*fy + r[5]) * depth + r[10];
                float Z = (r[6]*fx + r[7]*fy + r[8]) * depth + r[11];
                float iz = 1.0f / Z;
                float px = X * iz, py = Y * iz;
                float x0f = floorf(px), y0f = floorf(py);
                float wx = px - x0f, wy = py - y0f;
                int x0 = (int)x0f, y0 = (int)y0f;
#pragma unroll
                for (int t = 0; t < 4; t++) {
                    int xi = x0 + (t & 1), yi = y0 + (t >> 1);
                    float wgt = ((t & 1) ? wx : 1.0f - wx) * ((t >> 1) ? wy : 1.0f - wy);
                    bool valid = (xi >= 0) && (xi <= WW-1) && (yi >= 0) && (yi <= HH-1);
                    int xc = min(max(xi, 0), WW-1);
                    int yc = min(max(yi, 0), HH-1);
                    offs[v*4 + t] = yc*WW + xc;
                    wts[v*4 + t] = valid ? wgt : 0.0f;
                }
            }
#pragma unroll 4
            for (int c = 0; c < 32; c++) {
                float rv = f0[c*NP + p];
                float sum = rv, sq = rv * rv;
                const float* b1 = f1 + c*NP;
                float t1 = b1[offs[0]]*wts[0] + b1[offs[1]]*wts[1] + b1[offs[2]]*wts[2] + b1[offs[3]]*wts[3];
                const float* b2 = f2 + c*NP;
                float t2 = b2[offs[4]]*wts[4] + b2[offs[5]]*wts[5] + b2[offs[6]]*wts[6] + b2[offs[7]]*wts[7];
                sum += t1 + t2;
                sq  += t1*t1 + t2*t2;
                float m = sum * inv3;
                vs[c][hp] = sq * inv3 - m*m;
            }
#pragma unroll
            for (int c = 0; c < 8; c++) ss[c][hp] = s1[c*NP + p];
        }
    }
    __syncthreads();

    int px = threadIdx.x & 15, py = threadIdx.x >> 4;
    int base = py*HALO + px;   // tap (ky,kx) at base + ky*HALO + kx (halo origin -1)
    float acc[8];
#pragma unroll
    for (int o = 0; o < 8; o++) acc[o] = 0.0f;
    for (int ci = 0; ci < 32; ci++) {
        float t[9];
#pragma unroll
        for (int ky = 0; ky < 3; ky++)
#pragma unroll
            for (int kx = 0; kx < 3; kx++) t[ky*3+kx] = vs[ci][base + ky*HALO + kx];
#pragma unroll
        for (int o = 0; o < 8; o++) {
            const float* w = W0 + (o*32 + ci)*9;
            float a = acc[o];
#pragma unroll
            for (int k = 0; k < 9; k++) a += t[k] * w[k];
            acc[o] = a;
        }
    }
    for (int ci = 0; ci < 8; ci++) {
        float t[9];
#pragma unroll
        for (int ky = 0; ky < 3; ky++)
#pragma unroll
            for (int kx = 0; kx < 3; kx++) t[ky*3+kx] = ss[ci][base + ky*HALO + kx];
#pragma unroll
        for (int o = 0; o < 8; o++) {
            const float* w = Ws1 + (o*8 + ci)*9;
            float a = acc[o];
#pragma unroll
            for (int k = 0; k < 9; k++) a += t[k] * w[k];
            acc[o] = a;
        }
    }
    int p = (oy0 + py)*WW + ox0 + px;
#pragma unroll
    for (int o = 0; o < 8; o++) c1out[o*NP + p] = fmaxf(acc[o], 0.0f);
}

// ---- conv stage 2: c2 = relu(conv3x3s2(c1,W1) + conv3x3(s2,Ws2)), 16ch @ 160^2 ----
// blockIdx.y = out-channel group of 4
__global__ __launch_bounds__(256) void k_conv_b(
        const float* __restrict__ c1, const float* __restrict__ s2,
        const float* __restrict__ W1, const float* __restrict__ Ws2,
        float* __restrict__ c2) {
    int p = blockIdx.x*256 + threadIdx.x;
    if (p >= N2) return;
    int og = blockIdx.y;
    int y = p / W2, x = p - y*W2;
    int offsA[9]; float mskA[9];
#pragma unroll
    for (int k = 0; k < 9; k++) {
        int yy = 2*y + k/3, xx = 2*x + k%3;
        bool v = (yy < HH) && (xx < WW);
        offsA[k] = v ? yy*WW + xx : 0;
        mskA[k] = v ? 1.0f : 0.0f;
    }
    int offsB[9]; float mskB[9];
#pragma unroll
    for (int k = 0; k < 9; k++) {
        int yy = y + k/3 - 1, xx = x + k%3 - 1;
        bool v = (yy >= 0) && (yy < H2) && (xx >= 0) && (xx < W2);
        offsB[k] = v ? yy*W2 + xx : 0;
        mskB[k] = v ? 1.0f : 0.0f;
    }
    float acc[4];
#pragma unroll
    for (int o = 0; o < 4; o++) acc[o] = 0.0f;
    for (int ci = 0; ci < 8; ci++) {
        const float* b = c1 + ci*NP;
        float t[9];
#pragma unroll
        for (int k = 0; k < 9; k++) t[k] = b[offsA[k]] * mskA[k];
#pragma unroll
        for (int o = 0; o < 4; o++) {
            const float* w = W1 + ((og*4 + o)*8 + ci)*9;
            float a = acc[o];
#pragma unroll
            for (int k = 0; k < 9; k++) a += t[k] * w[k];
            acc[o] = a;
        }
    }
    for (int ci = 0; ci < 16; ci++) {
        const float* b = s2 + ci*N2;
        float t[9];
#pragma unroll
        for (int k = 0; k < 9; k++) t[k] = b[offsB[k]] * mskB[k];
#pragma unroll
        for (int o = 0; o < 4; o++) {
            const float* w = Ws2 + ((og*4 + o)*16 + ci)*9;
            float a = acc[o];
#pragma unroll
            for (int k = 0; k < 9; k++) a += t[k] * w[k];
            acc[o] = a;
        }
    }
#pragma unroll
    for (int o = 0; o < 4; o++) c2[(og*4 + o)*N2 + p] = fmaxf(acc[o], 0.0f);
}

// ---- conv stage 3: c3 = relu(conv3x3s2(c2,W2) + conv3x3(s3,Ws3)), 32ch @ 80^2 ----
__global__ __launch_bounds__(256) void k_conv_c(
        const float* __restrict__ c2, const float* __restrict__ s3,
        const float* __restrict__ W2w, const float* __restrict__ Ws3,
        float* __restrict__ c3) {
    int p = blockIdx.x*256 + threadIdx.x;
    if (p >= N4) return;
    int og = blockIdx.y;   // 8 groups of 4
    int y = p / W4, x = p - y*W4;
    int offsA[9]; float mskA[9];
#pragma unroll
    for (int k = 0; k < 9; k++) {
        int yy = 2*y + k/3, xx = 2*x + k%3;
        bool v = (yy < H2) && (xx < W2);
        offsA[k] = v ? yy*W2 + xx : 0;
        mskA[k] = v ? 1.0f : 0.0f;
    }
    int offsB[9]; float mskB[9];
#pragma unroll
    for (int k = 0; k < 9; k++) {
        int yy = y + k/3 - 1, xx = x + k%3 - 1;
        bool v = (yy >= 0) && (yy < H4) && (xx >= 0) && (xx < W4);
        offsB[k] = v ? yy*W4 + xx : 0;
        mskB[k] = v ? 1.0f : 0.0f;
    }
    float acc[4];
#pragma unroll
    for (int o = 0; o < 4; o++) acc[o] = 0.0f;
    for (int ci = 0; ci < 16; ci++) {
        const float* b = c2 + ci*N2;
        float t[9];
#pragma unroll
        for (int k = 0; k < 9; k++) t[k] = b[offsA[k]] * mskA[k];
#pragma unroll
        for (int o = 0; o < 4; o++) {
            const float* w = W2w + ((og*4 + o)*16 + ci)*9;
            float a = acc[o];
#pragma unroll
            for (int k = 0; k < 9; k++) a += t[k] * w[k];
            acc[o] = a;
        }
    }
    for (int ci = 0; ci < 32; ci++) {
        const float* b = s3 + ci*N4;
        float t[9];
#pragma unroll
        for (int k = 0; k < 9; k++) t[k] = b[offsB[k]] * mskB[k];
#pragma unroll
        for (int o = 0; o < 4; o++) {
            const float* w = Ws3 + ((og*4 + o)*32 + ci)*9;
            float a = acc[o];
#pragma unroll
            for (int k = 0; k < 9; k++) a += t[k] * w[k];
            acc[o] = a;
        }
    }
#pragma unroll
    for (int o = 0; o < 4; o++) c3[(og*4 + o)*N4 + p] = fmaxf(acc[o], 0.0f);
}

// ---- conv stage 4: c4 = relu(conv3x3s2(c3,W3) + conv3x3(s4,Ws4)), 64ch @ 40^2 ----
__global__ __launch_bounds__(256) void k_conv_d(
        const float* __restrict__ c3, const float* __restrict__ s4,
        const float* __restrict__ W3w, const float* __restrict__ Ws4,
        float* __restrict__ c4) {
    int p = blockIdx.x*256 + threadIdx.x;
    if (p >= N8) return;
    int og = blockIdx.y;   // 16 groups of 4
    int y = p / W8, x = p - y*W8;
    int offsA[9]; float mskA[9];
#pragma unroll
    for (int k = 0; k < 9; k++) {
        int yy = 2*y + k/3, xx = 2*x + k%3;
        bool v = (yy < H4) && (xx < W4);
        offsA[k] = v ? yy*W4 + xx : 0;
        mskA[k] = v ? 1.0f : 0.0f;
    }
    int offsB[9]; float mskB[9];
#pragma unroll
    for (int k = 0; k < 9; k++) {
        int yy = y + k/3 - 1, xx = x + k%3 - 1;
        bool v = (yy >= 0) && (yy < H8) && (xx >= 0) && (xx < W8);
        offsB[k] = v ? yy*W8 + xx : 0;
        mskB[k] = v ? 1.0f : 0.0f;
    }
    float acc[4];
#pragma unroll
    for (int o = 0; o < 4; o++) acc[o] = 0.0f;
    for (int ci = 0; ci < 32; ci++) {
        const float* b = c3 + ci*N4;
        float t[9];
#pragma unroll
        for (int k = 0; k < 9; k++) t[k] = b[offsA[k]] * mskA[k];
#pragma unroll
        for (int o = 0; o < 4; o++) {
            const float* w = W3w + ((og*4 + o)*32 + ci)*9;
            float a = acc[o];
#pragma unroll
            for (int k = 0; k < 9; k++) a += t[k] * w[k];
            acc[o] = a;
        }
    }
    for (int ci = 0; ci < 64; ci++) {
        const float* b = s4 + ci*N8;
        float t[9];
#pragma unroll
        for (int k = 0; k < 9; k++) t[k] = b[offsB[k]] * mskB[k];
#pragma unroll
        for (int o = 0; o < 4; o++) {
            const float* w = Ws4 + ((og*4 + o)*64 + ci)*9;
            float a = acc[o];
#pragma unroll
            for (int k = 0; k < 9; k++) a += t[k] * w[k];
            acc[o] = a;
        }
    }
#pragma unroll
    for (int o = 0; o < 4; o++) c4[(og*4 + o)*N8 + p] = fmaxf(acc[o], 0.0f);
}

// ---- fused up4+up3+up2+cost: per 16x16 output tile, pyramid recompute in LDS ----
__global__ __launch_bounds__(256) void k_up_cost(
        const float* __restrict__ c4, const float* __restrict__ c3,
        const float* __restrict__ c2, const float* __restrict__ c1,
        const float* __restrict__ U4, const float* __restrict__ U3,
        const float* __restrict__ U2, const float* __restrict__ Wout,
        const float* __restrict__ dslice,
        float* __restrict__ exp_sum, float* __restrict__ depth_img,
        float* __restrict__ max_prob) {
    __shared__ float u3s[32][36];    // 6x6 quarter-res
    __shared__ float u2s[16][100];   // 10x10 half-res
    __shared__ float u1s[8][NHALO];  // 18x18 full-res (zero-padded)
    int bx = blockIdx.x % 20, by = blockIdx.x / 20;
    int ox0 = bx*16, oy0 = by*16;
    int qy0 = (oy0 >> 2) - 1, qx0 = (ox0 >> 2) - 1;   // u3 region origin
    int hy0 = (oy0 >> 1) - 1, hx0 = (ox0 >> 1) - 1;   // u2 region origin

    // u3 = c3 + up2(conv1x1(c4,U4)) over 6x6 region
    for (int i = threadIdx.x; i < 32*36; i += 256) {
        int ch = i / 36, pp = i - ch*36;
        int y4 = qy0 + pp/6, x4 = qx0 + pp%6;
        int y4c = min(max(y4, 0), H4-1), x4c = min(max(x4, 0), W4-1);
        int pl = (y4c >> 1)*W8 + (x4c >> 1);
        const float* w = U4 + ch*64;
        float s = c3[ch*N4 + y4c*W4 + x4c];
#pragma unroll 8
        for (int ci = 0; ci < 64; ci++) s += c4[ci*N8 + pl] * w[ci];
        u3s[ch][pp] = s;
    }
    __syncthreads();
    // u2 = c2 + up2(conv1x1(u3,U3)) over 10x10 region
    for (int i = threadIdx.x; i < 16*100; i += 256) {
        int ch = i / 100, pp = i - ch*100;
        int y2 = hy0 + pp/10, x2 = hx0 + pp%10;
        int y2c = min(max(y2, 0), H2-1), x2c = min(max(x2, 0), W2-1);
        int ly = (y2c >> 1) - qy0, lx = (x2c >> 1) - qx0;
        const float* w = U3 + ch*32;
        float s = c2[ch*N2 + y2c*W2 + x2c];
#pragma unroll 8
        for (int ci = 0; ci < 32; ci++) s += u3s[ci][ly*6 + lx] * w[ci];
        u2s[ch][pp] = s;
    }
    __syncthreads();
    // u1 = c1 + up2(conv1x1(u2,U2)) over 18x18 halo (zero outside image)
    for (int i = threadIdx.x; i < 8*NHALO; i += 256) {
        int ch = i / NHALO, pp = i - ch*NHALO;
        int gy = oy0 + pp/HALO - 1, gx = ox0 + pp%HALO - 1;
        float s = 0.0f;
        if (gy >= 0 && gy < HH && gx >= 0 && gx < WW) {
            int ly = (gy >> 1) - hy0, lx = (gx >> 1) - hx0;
            const float* w = U2 + ch*16;
            s = c1[ch*NP + gy*WW + gx];
#pragma unroll
            for (int ci = 0; ci < 16; ci++) s += u2s[ci][ly*10 + lx] * w[ci];
        }
        u1s[ch][pp] = s;
    }
    __syncthreads();
    // cost = conv3x3(u1, Wout); prob accumulate
    int px = threadIdx.x & 15, py = threadIdx.x >> 4;
    int base = py*HALO + px;
    float cost = 0.0f;
#pragma unroll
    for (int ci = 0; ci < 8; ci++) {
        const float* w = Wout + ci*9;
#pragma unroll
        for (int ky = 0; ky < 3; ky++)
#pragma unroll
            for (int kx = 0; kx < 3; kx++)
                cost += u1s[ci][base + ky*HALO + kx] * w[ky*3 + kx];
    }
    int p = (oy0 + py)*WW + ox0 + px;
    float prob = expf(cost);
    exp_sum[p] += prob;
    depth_img[p] += dslice[p] * prob;
    max_prob[p] = fmaxf(max_prob[p], prob);
}

// ---------------- final normalize ----------------
__global__ __launch_bounds__(256) void k_final(
        const float* __restrict__ exp_sum, const float* __restrict__ depth_img,
        const float* __restrict__ max_prob, float* __restrict__ out) {
    int p = blockIdx.x*256 + threadIdx.x;
    if (p >= NP) return;
    float es = exp_sum[p] + 1e-10f;
    out[p] = depth_img[p] / es;
    out[NP + p] = max_prob[p] / es;
}

extern "C" void kernel_launch(void* const* d_in, const int* in_sizes, int n_in,
                              void* d_out, int out_size, void* d_ws, size_t ws_size,
                              hipStream_t stream) {
    const float* feats = (const float*)d_in[0];
    const float* proj  = (const float*)d_in[1];
    const float* depthv= (const float*)d_in[2];
    const float* W0  = (const float*)d_in[3];
    const float* Ws1 = (const float*)d_in[4];
    const float* W1  = (const float*)d_in[5];
    const float* Ws2 = (const float*)d_in[6];
    const float* W2w = (const float*)d_in[7];
    const float* Ws3 = (const float*)d_in[8];
    const float* W3w = (const float*)d_in[9];
    const float* Ws4 = (const float*)d_in[10];
    const float* U4  = (const float*)d_in[11];
    const float* U3  = (const float*)d_in[12];
    const float* U2  = (const float*)d_in[13];
    const float* Wout= (const float*)d_in[14];

    float* ws = (float*)d_ws;
    float* rel  = ws + OFF_REL;
    float* s1a  = ws + OFF_S1A;
    float* s2a  = ws + OFF_S2A;
    float* s3a  = ws + OFF_S3A;
    float* s4a  = ws + OFF_S4A;
    float* esum = ws + OFF_ESUM;
    float* dimg = ws + OFF_DIMG;
    float* maxp = ws + OFF_MAXP;
    float* s1b  = ws + OFF_S1B;
    float* s2b  = ws + OFF_S2B;
    float* s3b  = ws + OFF_S3B;
    float* s4b  = ws + OFF_S4B;

    // zero skip set A + accumulators (contiguous range)
    hipMemsetAsync(ws + OFF_S1A, 0, (size_t)(OFF_ZEND - OFF_S1A) * sizeof(float), stream);
    k_prep<<<1, 1, 0, stream>>>(proj, rel);

    for (int d = 0; d < DD; d++) {
        const float* dsl = depthv + (size_t)d * NP;
        float *rs1, *rs2, *rs3, *rs4, *wc1, *wc2, *wc3, *wc4;
        if ((d & 1) == 0) {
            rs1=s1a; rs2=s2a; rs3=s3a; rs4=s4a;
            wc1=s1b; wc2=s2b; wc3=s3b; wc4=s4b;
        } else {
            rs1=s1b; rs2=s2b; rs3=s3b; rs4=s4b;
            wc1=s1a; wc2=s2a; wc3=s3a; wc4=s4a;
        }
        k_warp_conv_a<<<dim3(400), 256, 0, stream>>>(feats, rel, dsl, rs1, W0, Ws1, wc1);
        k_conv_b<<<dim3(100, 4), 256, 0, stream>>>(wc1, rs2, W1, Ws2, wc2);
        k_conv_c<<<dim3(25, 8), 256, 0, stream>>>(wc2, rs3, W2w, Ws3, wc3);
        k_conv_d<<<dim3(7, 16), 256, 0, stream>>>(wc3, rs4, W3w, Ws4, wc4);
        k_up_cost<<<dim3(400), 256, 0, stream>>>(wc4, wc3, wc2, wc1, U4, U3, U2, Wout,
                                                 dsl, esum, dimg, maxp);
    }
    k_final<<<dim3(400), 256, 0, stream>>>(esum, dimg, maxp, (float*)d_out);
}

// Round 3
// 3172.688 us; speedup vs baseline: 2.4099x; 1.7395x over previous
//
#include <hip/hip_runtime.h>
#include <hip/hip_bf16.h>
#include <math.h>

// Problem constants
#define HH 320
#define WW 320
#define NP (HH*WW)        // 102400
#define CC 32
#define DD 32

#define H2 160
#define W2 160
#define N2 (H2*W2)        // 25600
#define H4 80
#define W4 80
#define N4 (H4*W4)        // 6400
#define H8 40
#define W8 40
#define N8 (H8*W8)        // 1600

#define HALO 18
#define NHALO (HALO*HALO) // 324

// ring strides (floats)
#define C1SZ (8*NP)       // 819200
#define C2SZ (16*N2)      // 409600
#define C3SZ (32*N4)      // 204800
#define C4SZ (64*N8)      // 102400

// ---------------- workspace layout (float offsets) ----------------
#define OFF_REL   0                        // 24 used, pad 64
#define OFF_C1R   64                       // ring of 5
#define OFF_C2R   (OFF_C1R + 5*C1SZ)       // ring of 4
#define OFF_C3R   (OFF_C2R + 4*C2SZ)       // ring of 3
#define OFF_C4R   (OFF_C3R + 3*C3SZ)       // ring of 2
#define OFF_ESUM  (OFF_C4R + 2*C4SZ)
#define OFF_DIMG  (OFF_ESUM + NP)
#define OFF_MAXP  (OFF_DIMG + NP)
#define OFF_END   (OFF_MAXP + NP)          // 6860864 floats ~ 26.2 MiB

// ---------------- prep: rel = proj[v] @ inv(proj[0]), v=1,2 ----------------
__global__ void k_prep(const float* __restrict__ proj, float* __restrict__ rel) {
    if (threadIdx.x != 0 || blockIdx.x != 0) return;
    double a[4][8];
    for (int i = 0; i < 4; i++)
        for (int j = 0; j < 4; j++) {
            a[i][j] = (double)proj[i*4 + j];
            a[i][j+4] = (i == j) ? 1.0 : 0.0;
        }
    for (int c = 0; c < 4; c++) {
        int pv = c; double best = fabs(a[c][c]);
        for (int r = c+1; r < 4; r++) {
            double v = fabs(a[r][c]);
            if (v > best) { best = v; pv = r; }
        }
        if (pv != c)
            for (int j = 0; j < 8; j++) { double t = a[c][j]; a[c][j] = a[pv][j]; a[pv][j] = t; }
        double inv = 1.0 / a[c][c];
        for (int j = 0; j < 8; j++) a[c][j] *= inv;
        for (int r = 0; r < 4; r++) if (r != c) {
            double f = a[r][c];
            for (int j = 0; j < 8; j++) a[r][j] -= f * a[c][j];
        }
    }
    for (int v = 1; v < 3; v++) {
        const float* P = proj + v*16;
        double rm[4][4];
        for (int i = 0; i < 4; i++)
            for (int j = 0; j < 4; j++) {
                double s = 0.0;
                for (int k = 0; k < 4; k++) s += (double)P[i*4 + k] * a[k][j+4];
                rm[i][j] = s;
            }
        float* o = rel + (v-1)*12;
        o[0]=(float)rm[0][0]; o[1]=(float)rm[0][1]; o[2]=(float)rm[0][2];
        o[3]=(float)rm[1][0]; o[4]=(float)rm[1][1]; o[5]=(float)rm[1][2];
        o[6]=(float)rm[2][0]; o[7]=(float)rm[2][1]; o[8]=(float)rm[2][2];
        o[9]=(float)rm[0][3]; o[10]=(float)rm[1][3]; o[11]=(float)rm[2][3];
    }
}

// ================= stage device functions =================

// A: warp+variance+conv1. blk in [0,400)
__device__ void stageA(int blk, int d,
        const float* __restrict__ feats, const float* __restrict__ rel,
        const float* __restrict__ depthv, const float* __restrict__ c1r,
        const float* __restrict__ W0, const float* __restrict__ Ws1,
        float* smem) {
    float* vs = smem;                 // [32][NHALO]
    float* ss = smem + 32*NHALO;      // [8][NHALO]
    const float* dslice = depthv + (size_t)d * NP;
    const float* s1 = c1r + (size_t)((d+4)%5) * C1SZ;   // c1_{d-1} (zeros for d=0)
    float* c1out = (float*)c1r + (size_t)(d%5) * C1SZ;

    int bx = blk % 20, by = blk / 20;
    int ox0 = bx*16, oy0 = by*16;

    const float* f0 = feats;
    const float* f1 = feats + CC*NP;
    const float* f2 = feats + 2*CC*NP;
    const float inv3 = 1.0f / 3.0f;

    for (int hp = threadIdx.x; hp < NHALO; hp += 256) {
        int hy = hp / HALO, hx = hp - hy*HALO;
        int gy = oy0 + hy - 1, gx = ox0 + hx - 1;
        if (gy < 0 || gy >= HH || gx < 0 || gx >= WW) {
#pragma unroll
            for (int c = 0; c < 32; c++) vs[c*NHALO + hp] = 0.0f;
#pragma unroll
            for (int c = 0; c < 8; c++) ss[c*NHALO + hp] = 0.0f;
        } else {
            int p = gy*WW + gx;
            float depth = dslice[p];
            float fx = (float)gx, fy = (float)gy;
            int offs[8]; float wts[8];
#pragma unroll
            for (int v = 0; v < 2; v++) {
                const float* r = rel + v*12;
                float X = (r[0]*fx + r[1]*fy + r[2]) * depth + r[9];
                float Y = (r[3]*fx + r[4]*fy + r[5]) * depth + r[10];
                float Z = (r[6]*fx + r[7]*fy + r[8]) * depth + r[11];
                float iz = 1.0f / Z;
                float px = X * iz, py = Y * iz;
                float x0f = floorf(px), y0f = floorf(py);
                float wx = px - x0f, wy = py - y0f;
                int x0 = (int)x0f, y0 = (int)y0f;
#pragma unroll
                for (int t = 0; t < 4; t++) {
                    int xi = x0 + (t & 1), yi = y0 + (t >> 1);
                    float wgt = ((t & 1) ? wx : 1.0f - wx) * ((t >> 1) ? wy : 1.0f - wy);
                    bool valid = (xi >= 0) && (xi <= WW-1) && (yi >= 0) && (yi <= HH-1);
                    int xc = min(max(xi, 0), WW-1);
                    int yc = min(max(yi, 0), HH-1);
                    offs[v*4 + t] = yc*WW + xc;
                    wts[v*4 + t] = valid ? wgt : 0.0f;
                }
            }
#pragma unroll 4
            for (int c = 0; c < 32; c++) {
                float rv = f0[c*NP + p];
                float sum = rv, sq = rv * rv;
                const float* b1 = f1 + c*NP;
                float t1 = b1[offs[0]]*wts[0] + b1[offs[1]]*wts[1] + b1[offs[2]]*wts[2] + b1[offs[3]]*wts[3];
                const float* b2 = f2 + c*NP;
                float t2 = b2[offs[4]]*wts[4] + b2[offs[5]]*wts[5] + b2[offs[6]]*wts[6] + b2[offs[7]]*wts[7];
                sum += t1 + t2;
                sq  += t1*t1 + t2*t2;
                float m = sum * inv3;
                vs[c*NHALO + hp] = sq * inv3 - m*m;
            }
#pragma unroll
            for (int c = 0; c < 8; c++) ss[c*NHALO + hp] = s1[c*NP + p];
        }
    }
    __syncthreads();

    int px = threadIdx.x & 15, py = threadIdx.x >> 4;
    int base = py*HALO + px;
    float acc[8];
#pragma unroll
    for (int o = 0; o < 8; o++) acc[o] = 0.0f;
    for (int ci = 0; ci < 32; ci++) {
        float t[9];
#pragma unroll
        for (int ky = 0; ky < 3; ky++)
#pragma unroll
            for (int kx = 0; kx < 3; kx++) t[ky*3+kx] = vs[ci*NHALO + base + ky*HALO + kx];
#pragma unroll
        for (int o = 0; o < 8; o++) {
            const float* w = W0 + (o*32 + ci)*9;
            float a = acc[o];
#pragma unroll
            for (int k = 0; k < 9; k++) a += t[k] * w[k];
            acc[o] = a;
        }
    }
    for (int ci = 0; ci < 8; ci++) {
        float t[9];
#pragma unroll
        for (int ky = 0; ky < 3; ky++)
#pragma unroll
            for (int kx = 0; kx < 3; kx++) t[ky*3+kx] = ss[ci*NHALO + base + ky*HALO + kx];
#pragma unroll
        for (int o = 0; o < 8; o++) {
            const float* w = Ws1 + (o*8 + ci)*9;
            float a = acc[o];
#pragma unroll
            for (int k = 0; k < 9; k++) a += t[k] * w[k];
            acc[o] = a;
        }
    }
    int p = (oy0 + py)*WW + ox0 + px;
#pragma unroll
    for (int o = 0; o < 8; o++) c1out[o*NP + p] = fmaxf(acc[o], 0.0f);
}

// B: conv2. blk in [0,400): px_chunk = blk%100, og = blk/100 (4 groups of 4)
__device__ void stageB(int blk, int d,
        const float* __restrict__ c1r, const float* __restrict__ c2r_,
        const float* __restrict__ W1, const float* __restrict__ Ws2) {
    const float* c1 = c1r + (size_t)(d%5) * C1SZ;
    const float* s2 = c2r_ + (size_t)((d+3)%4) * C2SZ;
    float* c2 = (float*)c2r_ + (size_t)(d%4) * C2SZ;
    int p = (blk % 100)*256 + threadIdx.x;
    if (p >= N2) return;
    int og = blk / 100;
    int y = p / W2, x = p - y*W2;
    int offsA[9]; float mskA[9];
#pragma unroll
    for (int k = 0; k < 9; k++) {
        int yy = 2*y + k/3, xx = 2*x + k%3;
        bool v = (yy < HH) && (xx < WW);
        offsA[k] = v ? yy*WW + xx : 0;
        mskA[k] = v ? 1.0f : 0.0f;
    }
    int offsB[9]; float mskB[9];
#pragma unroll
    for (int k = 0; k < 9; k++) {
        int yy = y + k/3 - 1, xx = x + k%3 - 1;
        bool v = (yy >= 0) && (yy < H2) && (xx >= 0) && (xx < W2);
        offsB[k] = v ? yy*W2 + xx : 0;
        mskB[k] = v ? 1.0f : 0.0f;
    }
    float acc[4];
#pragma unroll
    for (int o = 0; o < 4; o++) acc[o] = 0.0f;
    for (int ci = 0; ci < 8; ci++) {
        const float* b = c1 + ci*NP;
        float t[9];
#pragma unroll
        for (int k = 0; k < 9; k++) t[k] = b[offsA[k]] * mskA[k];
#pragma unroll
        for (int o = 0; o < 4; o++) {
            const float* w = W1 + ((og*4 + o)*8 + ci)*9;
            float a = acc[o];
#pragma unroll
            for (int k = 0; k < 9; k++) a += t[k] * w[k];
            acc[o] = a;
        }
    }
    for (int ci = 0; ci < 16; ci++) {
        const float* b = s2 + ci*N2;
        float t[9];
#pragma unroll
        for (int k = 0; k < 9; k++) t[k] = b[offsB[k]] * mskB[k];
#pragma unroll
        for (int o = 0; o < 4; o++) {
            const float* w = Ws2 + ((og*4 + o)*16 + ci)*9;
            float a = acc[o];
#pragma unroll
            for (int k = 0; k < 9; k++) a += t[k] * w[k];
            acc[o] = a;
        }
    }
#pragma unroll
    for (int o = 0; o < 4; o++) c2[(og*4 + o)*N2 + p] = fmaxf(acc[o], 0.0f);
}

// C: conv3. blk in [0,200): px_chunk = blk%25, og = blk/25 (8 groups of 4)
__device__ void stageC(int blk, int d,
        const float* __restrict__ c2r_, const float* __restrict__ c3r_,
        const float* __restrict__ W2w, const float* __restrict__ Ws3) {
    const float* c2 = c2r_ + (size_t)(d%4) * C2SZ;
    const float* s3 = c3r_ + (size_t)((d+2)%3) * C3SZ;
    float* c3 = (float*)c3r_ + (size_t)(d%3) * C3SZ;
    int p = (blk % 25)*256 + threadIdx.x;
    if (p >= N4) return;
    int og = blk / 25;
    int y = p / W4, x = p - y*W4;
    int offsA[9]; float mskA[9];
#pragma unroll
    for (int k = 0; k < 9; k++) {
        int yy = 2*y + k/3, xx = 2*x + k%3;
        bool v = (yy < H2) && (xx < W2);
        offsA[k] = v ? yy*W2 + xx : 0;
        mskA[k] = v ? 1.0f : 0.0f;
    }
    int offsB[9]; float mskB[9];
#pragma unroll
    for (int k = 0; k < 9; k++) {
        int yy = y + k/3 - 1, xx = x + k%3 - 1;
        bool v = (yy >= 0) && (yy < H4) && (xx >= 0) && (xx < W4);
        offsB[k] = v ? yy*W4 + xx : 0;
        mskB[k] = v ? 1.0f : 0.0f;
    }
    float acc[4];
#pragma unroll
    for (int o = 0; o < 4; o++) acc[o] = 0.0f;
    for (int ci = 0; ci < 16; ci++) {
        const float* b = c2 + ci*N2;
        float t[9];
#pragma unroll
        for (int k = 0; k < 9; k++) t[k] = b[offsA[k]] * mskA[k];
#pragma unroll
        for (int o = 0; o < 4; o++) {
            const float* w = W2w + ((og*4 + o)*16 + ci)*9;
            float a = acc[o];
#pragma unroll
            for (int k = 0; k < 9; k++) a += t[k] * w[k];
            acc[o] = a;
        }
    }
    for (int ci = 0; ci < 32; ci++) {
        const float* b = s3 + ci*N4;
        float t[9];
#pragma unroll
        for (int k = 0; k < 9; k++) t[k] = b[offsB[k]] * mskB[k];
#pragma unroll
        for (int o = 0; o < 4; o++) {
            const float* w = Ws3 + ((og*4 + o)*32 + ci)*9;
            float a = acc[o];
#pragma unroll
            for (int k = 0; k < 9; k++) a += t[k] * w[k];
            acc[o] = a;
        }
    }
#pragma unroll
    for (int o = 0; o < 4; o++) c3[(og*4 + o)*N4 + p] = fmaxf(acc[o], 0.0f);
}

// D: conv4. blk in [0,112): px_chunk = blk%7, og = blk/7 (16 groups of 4)
__device__ void stageD(int blk, int d,
        const float* __restrict__ c3r_, const float* __restrict__ c4r_,
        const float* __restrict__ W3w, const float* __restrict__ Ws4) {
    const float* c3 = c3r_ + (size_t)(d%3) * C3SZ;
    const float* s4 = c4r_ + (size_t)((d+1)%2) * C4SZ;
    float* c4 = (float*)c4r_ + (size_t)(d%2) * C4SZ;
    int p = (blk % 7)*256 + threadIdx.x;
    if (p >= N8) return;
    int og = blk / 7;
    int y = p / W8, x = p - y*W8;
    int offsA[9]; float mskA[9];
#pragma unroll
    for (int k = 0; k < 9; k++) {
        int yy = 2*y + k/3, xx = 2*x + k%3;
        bool v = (yy < H4) && (xx < W4);
        offsA[k] = v ? yy*W4 + xx : 0;
        mskA[k] = v ? 1.0f : 0.0f;
    }
    int offsB[9]; float mskB[9];
#pragma unroll
    for (int k = 0; k < 9; k++) {
        int yy = y + k/3 - 1, xx = x + k%3 - 1;
        bool v = (yy >= 0) && (yy < H8) && (xx >= 0) && (xx < W8);
        offsB[k] = v ? yy*W8 + xx : 0;
        mskB[k] = v ? 1.0f : 0.0f;
    }
    float acc[4];
#pragma unroll
    for (int o = 0; o < 4; o++) acc[o] = 0.0f;
    for (int ci = 0; ci < 32; ci++) {
        const float* b = c3 + ci*N4;
        float t[9];
#pragma unroll
        for (int k = 0; k < 9; k++) t[k] = b[offsA[k]] * mskA[k];
#pragma unroll
        for (int o = 0; o < 4; o++) {
            const float* w = W3w + ((og*4 + o)*32 + ci)*9;
            float a = acc[o];
#pragma unroll
            for (int k = 0; k < 9; k++) a += t[k] * w[k];
            acc[o] = a;
        }
    }
    for (int ci = 0; ci < 64; ci++) {
        const float* b = s4 + ci*N8;
        float t[9];
#pragma unroll
        for (int k = 0; k < 9; k++) t[k] = b[offsB[k]] * mskB[k];
#pragma unroll
        for (int o = 0; o < 4; o++) {
            const float* w = Ws4 + ((og*4 + o)*64 + ci)*9;
            float a = acc[o];
#pragma unroll
            for (int k = 0; k < 9; k++) a += t[k] * w[k];
            acc[o] = a;
        }
    }
#pragma unroll
    for (int o = 0; o < 4; o++) c4[(og*4 + o)*N8 + p] = fmaxf(acc[o], 0.0f);
}

// U: up4+up3+up2+cost+accumulate. blk in [0,400)
__device__ void stageU(int blk, int d,
        const float* __restrict__ c1r, const float* __restrict__ c2r_,
        const float* __restrict__ c3r_, const float* __restrict__ c4r_,
        const float* __restrict__ U4, const float* __restrict__ U3,
        const float* __restrict__ U2, const float* __restrict__ Wout,
        const float* __restrict__ depthv,
        float* __restrict__ exp_sum, float* __restrict__ depth_img,
        float* __restrict__ max_prob, float* smem) {
    const float* c1 = c1r + (size_t)(d%5) * C1SZ;
    const float* c2 = c2r_ + (size_t)(d%4) * C2SZ;
    const float* c3 = c3r_ + (size_t)(d%3) * C3SZ;
    const float* c4 = c4r_ + (size_t)(d%2) * C4SZ;
    const float* dslice = depthv + (size_t)d * NP;
    float* u3s = smem;               // [32][36]
    float* u2s = smem + 32*36;       // [16][100]
    float* u1s = smem + 32*36 + 16*100; // [8][NHALO]

    int bx = blk % 20, by = blk / 20;
    int ox0 = bx*16, oy0 = by*16;
    int qy0 = (oy0 >> 2) - 1, qx0 = (ox0 >> 2) - 1;
    int hy0 = (oy0 >> 1) - 1, hx0 = (ox0 >> 1) - 1;

    for (int i = threadIdx.x; i < 32*36; i += 256) {
        int ch = i / 36, pp = i - ch*36;
        int y4 = qy0 + pp/6, x4 = qx0 + pp%6;
        int y4c = min(max(y4, 0), H4-1), x4c = min(max(x4, 0), W4-1);
        int pl = (y4c >> 1)*W8 + (x4c >> 1);
        const float* w = U4 + ch*64;
        float s = c3[ch*N4 + y4c*W4 + x4c];
#pragma unroll 8
        for (int ci = 0; ci < 64; ci++) s += c4[ci*N8 + pl] * w[ci];
        u3s[ch*36 + pp] = s;
    }
    __syncthreads();
    for (int i = threadIdx.x; i < 16*100; i += 256) {
        int ch = i / 100, pp = i - ch*100;
        int y2 = hy0 + pp/10, x2 = hx0 + pp%10;
        int y2c = min(max(y2, 0), H2-1), x2c = min(max(x2, 0), W2-1);
        int ly = (y2c >> 1) - qy0, lx = (x2c >> 1) - qx0;
        const float* w = U3 + ch*32;
        float s = c2[ch*N2 + y2c*W2 + x2c];
#pragma unroll 8
        for (int ci = 0; ci < 32; ci++) s += u3s[ci*36 + ly*6 + lx] * w[ci];
        u2s[ch*100 + pp] = s;
    }
    __syncthreads();
    for (int i = threadIdx.x; i < 8*NHALO; i += 256) {
        int ch = i / NHALO, pp = i - ch*NHALO;
        int gy = oy0 + pp/HALO - 1, gx = ox0 + pp%HALO - 1;
        float s = 0.0f;
        if (gy >= 0 && gy < HH && gx >= 0 && gx < WW) {
            int ly = (gy >> 1) - hy0, lx = (gx >> 1) - hx0;
            const float* w = U2 + ch*16;
            s = c1[ch*NP + gy*WW + gx];
#pragma unroll
            for (int ci = 0; ci < 16; ci++) s += u2s[ci*100 + ly*10 + lx] * w[ci];
        }
        u1s[ch*NHALO + pp] = s;
    }
    __syncthreads();
    int px = threadIdx.x & 15, py = threadIdx.x >> 4;
    int base = py*HALO + px;
    float cost = 0.0f;
#pragma unroll
    for (int ci = 0; ci < 8; ci++) {
        const float* w = Wout + ci*9;
#pragma unroll
        for (int ky = 0; ky < 3; ky++)
#pragma unroll
            for (int kx = 0; kx < 3; kx++)
                cost += u1s[ci*NHALO + base + ky*HALO + kx] * w[ky*3 + kx];
    }
    int p = (oy0 + py)*WW + ox0 + px;
    float prob = expf(cost);
    exp_sum[p] += prob;
    depth_img[p] += dslice[p] * prob;
    max_prob[p] = fmaxf(max_prob[p], prob);
}

// ================= uber kernel: one diagonal of the pipeline =================
__global__ __launch_bounds__(256) void k_uber(
        int t,
        const float* __restrict__ feats, const float* __restrict__ rel,
        const float* __restrict__ depthv,
        const float* __restrict__ W0, const float* __restrict__ Ws1,
        const float* __restrict__ W1, const float* __restrict__ Ws2,
        const float* __restrict__ W2w, const float* __restrict__ Ws3,
        const float* __restrict__ W3w, const float* __restrict__ Ws4,
        const float* __restrict__ U4, const float* __restrict__ U3,
        const float* __restrict__ U2, const float* __restrict__ Wout,
        float* __restrict__ c1r, float* __restrict__ c2r,
        float* __restrict__ c3r, float* __restrict__ c4r,
        float* __restrict__ esum, float* __restrict__ dimg,
        float* __restrict__ maxp) {
    __shared__ float smem[32*NHALO + 8*NHALO];   // 51840 B (union; stage U uses a prefix)
    int b = blockIdx.x;
    if (b < 400) {
        int d = t;
        if (d < DD) stageA(b, d, feats, rel, depthv, c1r, W0, Ws1, smem);
    } else if (b < 800) {
        int d = t - 1;
        if (d >= 0 && d < DD) stageB(b - 400, d, c1r, c2r, W1, Ws2);
    } else if (b < 1000) {
        int d = t - 2;
        if (d >= 0 && d < DD) stageC(b - 800, d, c2r, c3r, W2w, Ws3);
    } else if (b < 1112) {
        int d = t - 3;
        if (d >= 0 && d < DD) stageD(b - 1000, d, c3r, c4r, W3w, Ws4);
    } else {
        int d = t - 4;
        if (d >= 0 && d < DD)
            stageU(b - 1112, d, c1r, c2r, c3r, c4r, U4, U3, U2, Wout, depthv,
                   esum, dimg, maxp, smem);
    }
}

// ---------------- final normalize ----------------
__global__ __launch_bounds__(256) void k_final(
        const float* __restrict__ exp_sum, const float* __restrict__ depth_img,
        const float* __restrict__ max_prob, float* __restrict__ out) {
    int p = blockIdx.x*256 + threadIdx.x;
    if (p >= NP) return;
    float es = exp_sum[p] + 1e-10f;
    out[p] = depth_img[p] / es;
    out[NP + p] = max_prob[p] / es;
}

extern "C" void kernel_launch(void* const* d_in, const int* in_sizes, int n_in,
                              void* d_out, int out_size, void* d_ws, size_t ws_size,
                              hipStream_t stream) {
    const float* feats = (const float*)d_in[0];
    const float* proj  = (const float*)d_in[1];
    const float* depthv= (const float*)d_in[2];
    const float* W0  = (const float*)d_in[3];
    const float* Ws1 = (const float*)d_in[4];
    const float* W1  = (const float*)d_in[5];
    const float* Ws2 = (const float*)d_in[6];
    const float* W2w = (const float*)d_in[7];
    const float* Ws3 = (const float*)d_in[8];
    const float* W3w = (const float*)d_in[9];
    const float* Ws4 = (const float*)d_in[10];
    const float* U4  = (const float*)d_in[11];
    const float* U3  = (const float*)d_in[12];
    const float* U2  = (const float*)d_in[13];
    const float* Wout= (const float*)d_in[14];

    float* ws = (float*)d_ws;
    float* rel  = ws + OFF_REL;
    float* c1r  = ws + OFF_C1R;
    float* c2r  = ws + OFF_C2R;
    float* c3r  = ws + OFF_C3R;
    float* c4r  = ws + OFF_C4R;
    float* esum = ws + OFF_ESUM;
    float* dimg = ws + OFF_DIMG;
    float* maxp = ws + OFF_MAXP;

    // zero all rings + accumulators (ws is poisoned 0xAA before every call);
    // ring slots double as the zero "previous skip" inputs for d=0.
    hipMemsetAsync(c1r, 0, (size_t)(OFF_END - OFF_C1R) * sizeof(float), stream);
    k_prep<<<1, 1, 0, stream>>>(proj, rel);

    for (int t = 0; t < DD + 4; t++) {
        k_uber<<<dim3(1512), 256, 0, stream>>>(t, feats, rel, depthv,
            W0, Ws1, W1, Ws2, W2w, Ws3, W3w, Ws4, U4, U3, U2, Wout,
            c1r, c2r, c3r, c4r, esum, dimg, maxp);
    }
    k_final<<<dim3(400), 256, 0, stream>>>(esum, dimg, maxp, (float*)d_out);
}

// Round 4
// 2993.951 us; speedup vs baseline: 2.5538x; 1.0597x over previous
//
#include <hip/hip_runtime.h>
#include <hip/hip_bf16.h>
#include <math.h>

// Problem constants
#define HH 320
#define WW 320
#define NP (HH*WW)        // 102400
#define CC 32
#define DD 32

#define H2 160
#define W2 160
#define N2 (H2*W2)        // 25600
#define H4 80
#define W4 80
#define N4 (H4*W4)        // 6400
#define H8 40
#define W8 40
#define N8 (H8*W8)        // 1600

#define HALO 18
#define NHALO (HALO*HALO) // 324

// ring strides (floats)
#define C1SZ (8*NP)       // 819200
#define C2SZ (16*N2)      // 409600
#define C3SZ (32*N4)      // 204800
#define C4SZ (64*N8)      // 102400

// uber-kernel shared memory (floats): max(stageA = 8*NHALO, stageU = 32*36+16*100+8*NHALO)
#define SMEM_FLOATS (32*36 + 16*100 + 8*NHALO)   // 5344 floats = 21376 B -> 7 blocks/CU

// ---------------- workspace layout (float offsets) ----------------
#define OFF_REL   0                        // 24 used, pad 64
#define OFF_C1R   64                       // ring of 5
#define OFF_C2R   (OFF_C1R + 5*C1SZ)       // ring of 4
#define OFF_C3R   (OFF_C2R + 4*C2SZ)       // ring of 3
#define OFF_C4R   (OFF_C3R + 3*C3SZ)       // ring of 2
#define OFF_ESUM  (OFF_C4R + 2*C4SZ)
#define OFF_DIMG  (OFF_ESUM + NP)
#define OFF_MAXP  (OFF_DIMG + NP)
#define OFF_END   (OFF_MAXP + NP)          // ~26.2 MiB

// ---------------- prep: rel = proj[v] @ inv(proj[0]), v=1,2 ----------------
__global__ void k_prep(const float* __restrict__ proj, float* __restrict__ rel) {
    if (threadIdx.x != 0 || blockIdx.x != 0) return;
    double a[4][8];
    for (int i = 0; i < 4; i++)
        for (int j = 0; j < 4; j++) {
            a[i][j] = (double)proj[i*4 + j];
            a[i][j+4] = (i == j) ? 1.0 : 0.0;
        }
    for (int c = 0; c < 4; c++) {
        int pv = c; double best = fabs(a[c][c]);
        for (int r = c+1; r < 4; r++) {
            double v = fabs(a[r][c]);
            if (v > best) { best = v; pv = r; }
        }
        if (pv != c)
            for (int j = 0; j < 8; j++) { double t = a[c][j]; a[c][j] = a[pv][j]; a[pv][j] = t; }
        double inv = 1.0 / a[c][c];
        for (int j = 0; j < 8; j++) a[c][j] *= inv;
        for (int r = 0; r < 4; r++) if (r != c) {
            double f = a[r][c];
            for (int j = 0; j < 8; j++) a[r][j] -= f * a[c][j];
        }
    }
    for (int v = 1; v < 3; v++) {
        const float* P = proj + v*16;
        double rm[4][4];
        for (int i = 0; i < 4; i++)
            for (int j = 0; j < 4; j++) {
                double s = 0.0;
                for (int k = 0; k < 4; k++) s += (double)P[i*4 + k] * a[k][j+4];
                rm[i][j] = s;
            }
        float* o = rel + (v-1)*12;
        o[0]=(float)rm[0][0]; o[1]=(float)rm[0][1]; o[2]=(float)rm[0][2];
        o[3]=(float)rm[1][0]; o[4]=(float)rm[1][1]; o[5]=(float)rm[1][2];
        o[6]=(float)rm[2][0]; o[7]=(float)rm[2][1]; o[8]=(float)rm[2][2];
        o[9]=(float)rm[0][3]; o[10]=(float)rm[1][3]; o[11]=(float)rm[2][3];
    }
}

// ================= stage device functions =================

// A: warp+variance+conv1, channel-chunked through an [8][NHALO] LDS buffer.
// blk in [0,400)
__device__ void stageA(int blk, int d,
        const float* __restrict__ feats, const float* __restrict__ rel,
        const float* __restrict__ depthv, const float* __restrict__ c1r,
        const float* __restrict__ W0, const float* __restrict__ Ws1,
        float* buf) {
    const float* dslice = depthv + (size_t)d * NP;
    const float* s1 = c1r + (size_t)((d+4)%5) * C1SZ;   // c1_{d-1} (zeros for d=0)
    float* c1out = (float*)c1r + (size_t)(d%5) * C1SZ;

    int bx = blk % 20, by = blk / 20;
    int ox0 = bx*16, oy0 = by*16;

    const float* f1 = feats + CC*NP;
    const float* f2 = feats + 2*CC*NP;
    const float inv3 = 1.0f / 3.0f;

    int opx = threadIdx.x & 15, opy = threadIdx.x >> 4;
    int obase = opy*HALO + opx;
    int outp = (oy0 + opy)*WW + ox0 + opx;

    float acc[8];
#pragma unroll
    for (int o = 0; o < 8; o++) acc[o] = 0.0f;

    // 4 chunks of 8 variance channels
    for (int chunk = 0; chunk < 4; chunk++) {
        int cbase = chunk*8;
        for (int hp = threadIdx.x; hp < NHALO; hp += 256) {
            int hy = hp / HALO, hx = hp - hy*HALO;
            int gy = oy0 + hy - 1, gx = ox0 + hx - 1;
            if (gy < 0 || gy >= HH || gx < 0 || gx >= WW) {
#pragma unroll
                for (int c = 0; c < 8; c++) buf[c*NHALO + hp] = 0.0f;
            } else {
                int p = gy*WW + gx;
                float depth = dslice[p];
                float fx = (float)gx, fy = (float)gy;
                int offs[8]; float wts[8];
#pragma unroll
                for (int v = 0; v < 2; v++) {
                    const float* r = rel + v*12;
                    float X = (r[0]*fx + r[1]*fy + r[2]) * depth + r[9];
                    float Y = (r[3]*fx + r[4]*fy + r[5]) * depth + r[10];
                    float Z = (r[6]*fx + r[7]*fy + r[8]) * depth + r[11];
                    float iz = 1.0f / Z;
                    float px = X * iz, py = Y * iz;
                    float x0f = floorf(px), y0f = floorf(py);
                    float wx = px - x0f, wy = py - y0f;
                    int x0 = (int)x0f, y0 = (int)y0f;
#pragma unroll
                    for (int t = 0; t < 4; t++) {
                        int xi = x0 + (t & 1), yi = y0 + (t >> 1);
                        float wgt = ((t & 1) ? wx : 1.0f - wx) * ((t >> 1) ? wy : 1.0f - wy);
                        bool valid = (xi >= 0) && (xi <= WW-1) && (yi >= 0) && (yi <= HH-1);
                        int xc = min(max(xi, 0), WW-1);
                        int yc = min(max(yi, 0), HH-1);
                        offs[v*4 + t] = yc*WW + xc;
                        wts[v*4 + t] = valid ? wgt : 0.0f;
                    }
                }
#pragma unroll
                for (int c = 0; c < 8; c++) {
                    int cg = cbase + c;
                    float rv = feats[cg*NP + p];
                    float sum = rv, sq = rv * rv;
                    const float* b1 = f1 + cg*NP;
                    float t1 = b1[offs[0]]*wts[0] + b1[offs[1]]*wts[1] + b1[offs[2]]*wts[2] + b1[offs[3]]*wts[3];
                    const float* b2 = f2 + cg*NP;
                    float t2 = b2[offs[4]]*wts[4] + b2[offs[5]]*wts[5] + b2[offs[6]]*wts[6] + b2[offs[7]]*wts[7];
                    sum += t1 + t2;
                    sq  += t1*t1 + t2*t2;
                    float m = sum * inv3;
                    buf[c*NHALO + hp] = sq * inv3 - m*m;
                }
            }
        }
        __syncthreads();
        for (int ci = 0; ci < 8; ci++) {
            float t[9];
#pragma unroll
            for (int ky = 0; ky < 3; ky++)
#pragma unroll
                for (int kx = 0; kx < 3; kx++) t[ky*3+kx] = buf[ci*NHALO + obase + ky*HALO + kx];
#pragma unroll
            for (int o = 0; o < 8; o++) {
                const float* w = W0 + (o*32 + cbase + ci)*9;
                float a = acc[o];
#pragma unroll
                for (int k = 0; k < 9; k++) a += t[k] * w[k];
                acc[o] = a;
            }
        }
        __syncthreads();   // before next chunk overwrites buf
    }

    // s1 chunk (8 channels)
    for (int hp = threadIdx.x; hp < NHALO; hp += 256) {
        int hy = hp / HALO, hx = hp - hy*HALO;
        int gy = oy0 + hy - 1, gx = ox0 + hx - 1;
        bool v = (gy >= 0) && (gy < HH) && (gx >= 0) && (gx < WW);
        int p = v ? gy*WW + gx : 0;
#pragma unroll
        for (int c = 0; c < 8; c++) buf[c*NHALO + hp] = v ? s1[c*NP + p] : 0.0f;
    }
    __syncthreads();
    for (int ci = 0; ci < 8; ci++) {
        float t[9];
#pragma unroll
        for (int ky = 0; ky < 3; ky++)
#pragma unroll
            for (int kx = 0; kx < 3; kx++) t[ky*3+kx] = buf[ci*NHALO + obase + ky*HALO + kx];
#pragma unroll
        for (int o = 0; o < 8; o++) {
            const float* w = Ws1 + (o*8 + ci)*9;
            float a = acc[o];
#pragma unroll
            for (int k = 0; k < 9; k++) a += t[k] * w[k];
            acc[o] = a;
        }
    }
#pragma unroll
    for (int o = 0; o < 8; o++) c1out[o*NP + outp] = fmaxf(acc[o], 0.0f);
}

// B: conv2. blk in [0,400): px_chunk = blk%100, og = blk/100 (4 groups of 4)
__device__ void stageB(int blk, int d,
        const float* __restrict__ c1r, const float* __restrict__ c2r_,
        const float* __restrict__ W1, const float* __restrict__ Ws2) {
    const float* c1 = c1r + (size_t)(d%5) * C1SZ;
    const float* s2 = c2r_ + (size_t)((d+3)%4) * C2SZ;
    float* c2 = (float*)c2r_ + (size_t)(d%4) * C2SZ;
    int p = (blk % 100)*256 + threadIdx.x;
    if (p >= N2) return;
    int og = blk / 100;
    int y = p / W2, x = p - y*W2;
    int offsA[9]; float mskA[9];
#pragma unroll
    for (int k = 0; k < 9; k++) {
        int yy = 2*y + k/3, xx = 2*x + k%3;
        bool v = (yy < HH) && (xx < WW);
        offsA[k] = v ? yy*WW + xx : 0;
        mskA[k] = v ? 1.0f : 0.0f;
    }
    int offsB[9]; float mskB[9];
#pragma unroll
    for (int k = 0; k < 9; k++) {
        int yy = y + k/3 - 1, xx = x + k%3 - 1;
        bool v = (yy >= 0) && (yy < H2) && (xx >= 0) && (xx < W2);
        offsB[k] = v ? yy*W2 + xx : 0;
        mskB[k] = v ? 1.0f : 0.0f;
    }
    float acc[4];
#pragma unroll
    for (int o = 0; o < 4; o++) acc[o] = 0.0f;
    for (int ci = 0; ci < 8; ci++) {
        const float* b = c1 + ci*NP;
        float t[9];
#pragma unroll
        for (int k = 0; k < 9; k++) t[k] = b[offsA[k]] * mskA[k];
#pragma unroll
        for (int o = 0; o < 4; o++) {
            const float* w = W1 + ((og*4 + o)*8 + ci)*9;
            float a = acc[o];
#pragma unroll
            for (int k = 0; k < 9; k++) a += t[k] * w[k];
            acc[o] = a;
        }
    }
    for (int ci = 0; ci < 16; ci++) {
        const float* b = s2 + ci*N2;
        float t[9];
#pragma unroll
        for (int k = 0; k < 9; k++) t[k] = b[offsB[k]] * mskB[k];
#pragma unroll
        for (int o = 0; o < 4; o++) {
            const float* w = Ws2 + ((og*4 + o)*16 + ci)*9;
            float a = acc[o];
#pragma unroll
            for (int k = 0; k < 9; k++) a += t[k] * w[k];
            acc[o] = a;
        }
    }
#pragma unroll
    for (int o = 0; o < 4; o++) c2[(og*4 + o)*N2 + p] = fmaxf(acc[o], 0.0f);
}

// C: conv3. blk in [0,200): px_chunk = blk%25, og = blk/25 (8 groups of 4)
__device__ void stageC(int blk, int d,
        const float* __restrict__ c2r_, const float* __restrict__ c3r_,
        const float* __restrict__ W2w, const float* __restrict__ Ws3) {
    const float* c2 = c2r_ + (size_t)(d%4) * C2SZ;
    const float* s3 = c3r_ + (size_t)((d+2)%3) * C3SZ;
    float* c3 = (float*)c3r_ + (size_t)(d%3) * C3SZ;
    int p = (blk % 25)*256 + threadIdx.x;
    if (p >= N4) return;
    int og = blk / 25;
    int y = p / W4, x = p - y*W4;
    int offsA[9]; float mskA[9];
#pragma unroll
    for (int k = 0; k < 9; k++) {
        int yy = 2*y + k/3, xx = 2*x + k%3;
        bool v = (yy < H2) && (xx < W2);
        offsA[k] = v ? yy*W2 + xx : 0;
        mskA[k] = v ? 1.0f : 0.0f;
    }
    int offsB[9]; float mskB[9];
#pragma unroll
    for (int k = 0; k < 9; k++) {
        int yy = y + k/3 - 1, xx = x + k%3 - 1;
        bool v = (yy >= 0) && (yy < H4) && (xx >= 0) && (xx < W4);
        offsB[k] = v ? yy*W4 + xx : 0;
        mskB[k] = v ? 1.0f : 0.0f;
    }
    float acc[4];
#pragma unroll
    for (int o = 0; o < 4; o++) acc[o] = 0.0f;
    for (int ci = 0; ci < 16; ci++) {
        const float* b = c2 + ci*N2;
        float t[9];
#pragma unroll
        for (int k = 0; k < 9; k++) t[k] = b[offsA[k]] * mskA[k];
#pragma unroll
        for (int o = 0; o < 4; o++) {
            const float* w = W2w + ((og*4 + o)*16 + ci)*9;
            float a = acc[o];
#pragma unroll
            for (int k = 0; k < 9; k++) a += t[k] * w[k];
            acc[o] = a;
        }
    }
    for (int ci = 0; ci < 32; ci++) {
        const float* b = s3 + ci*N4;
        float t[9];
#pragma unroll
        for (int k = 0; k < 9; k++) t[k] = b[offsB[k]] * mskB[k];
#pragma unroll
        for (int o = 0; o < 4; o++) {
            const float* w = Ws3 + ((og*4 + o)*32 + ci)*9;
            float a = acc[o];
#pragma unroll
            for (int k = 0; k < 9; k++) a += t[k] * w[k];
            acc[o] = a;
        }
    }
#pragma unroll
    for (int o = 0; o < 4; o++) c3[(og*4 + o)*N4 + p] = fmaxf(acc[o], 0.0f);
}

// D: conv4. blk in [0,112): px_chunk = blk%7, og = blk/7 (16 groups of 4)
__device__ void stageD(int blk, int d,
        const float* __restrict__ c3r_, const float* __restrict__ c4r_,
        const float* __restrict__ W3w, const float* __restrict__ Ws4) {
    const float* c3 = c3r_ + (size_t)(d%3) * C3SZ;
    const float* s4 = c4r_ + (size_t)((d+1)%2) * C4SZ;
    float* c4 = (float*)c4r_ + (size_t)(d%2) * C4SZ;
    int p = (blk % 7)*256 + threadIdx.x;
    if (p >= N8) return;
    int og = blk / 7;
    int y = p / W8, x = p - y*W8;
    int offsA[9]; float mskA[9];
#pragma unroll
    for (int k = 0; k < 9; k++) {
        int yy = 2*y + k/3, xx = 2*x + k%3;
        bool v = (yy < H4) && (xx < W4);
        offsA[k] = v ? yy*W4 + xx : 0;
        mskA[k] = v ? 1.0f : 0.0f;
    }
    int offsB[9]; float mskB[9];
#pragma unroll
    for (int k = 0; k < 9; k++) {
        int yy = y + k/3 - 1, xx = x + k%3 - 1;
        bool v = (yy >= 0) && (yy < H8) && (xx >= 0) && (xx < W8);
        offsB[k] = v ? yy*W8 + xx : 0;
        mskB[k] = v ? 1.0f : 0.0f;
    }
    float acc[4];
#pragma unroll
    for (int o = 0; o < 4; o++) acc[o] = 0.0f;
    for (int ci = 0; ci < 32; ci++) {
        const float* b = c3 + ci*N4;
        float t[9];
#pragma unroll
        for (int k = 0; k < 9; k++) t[k] = b[offsA[k]] * mskA[k];
#pragma unroll
        for (int o = 0; o < 4; o++) {
            const float* w = W3w + ((og*4 + o)*32 + ci)*9;
            float a = acc[o];
#pragma unroll
            for (int k = 0; k < 9; k++) a += t[k] * w[k];
            acc[o] = a;
        }
    }
    for (int ci = 0; ci < 64; ci++) {
        const float* b = s4 + ci*N8;
        float t[9];
#pragma unroll
        for (int k = 0; k < 9; k++) t[k] = b[offsB[k]] * mskB[k];
#pragma unroll
        for (int o = 0; o < 4; o++) {
            const float* w = Ws4 + ((og*4 + o)*64 + ci)*9;
            float a = acc[o];
#pragma unroll
            for (int k = 0; k < 9; k++) a += t[k] * w[k];
            acc[o] = a;
        }
    }
#pragma unroll
    for (int o = 0; o < 4; o++) c4[(og*4 + o)*N8 + p] = fmaxf(acc[o], 0.0f);
}

// U: up4+up3+up2+cost+accumulate. blk in [0,400)
__device__ void stageU(int blk, int d,
        const float* __restrict__ c1r, const float* __restrict__ c2r_,
        const float* __restrict__ c3r_, const float* __restrict__ c4r_,
        const float* __restrict__ U4, const float* __restrict__ U3,
        const float* __restrict__ U2, const float* __restrict__ Wout,
        const float* __restrict__ depthv,
        float* __restrict__ exp_sum, float* __restrict__ depth_img,
        float* __restrict__ max_prob, float* smem) {
    const float* c1 = c1r + (size_t)(d%5) * C1SZ;
    const float* c2 = c2r_ + (size_t)(d%4) * C2SZ;
    const float* c3 = c3r_ + (size_t)(d%3) * C3SZ;
    const float* c4 = c4r_ + (size_t)(d%2) * C4SZ;
    const float* dslice = depthv + (size_t)d * NP;
    float* u3s = smem;               // [32][36]
    float* u2s = smem + 32*36;       // [16][100]
    float* u1s = smem + 32*36 + 16*100; // [8][NHALO]

    int bx = blk % 20, by = blk / 20;
    int ox0 = bx*16, oy0 = by*16;
    int qy0 = (oy0 >> 2) - 1, qx0 = (ox0 >> 2) - 1;
    int hy0 = (oy0 >> 1) - 1, hx0 = (ox0 >> 1) - 1;

    for (int i = threadIdx.x; i < 32*36; i += 256) {
        int ch = i / 36, pp = i - ch*36;
        int y4 = qy0 + pp/6, x4 = qx0 + pp%6;
        int y4c = min(max(y4, 0), H4-1), x4c = min(max(x4, 0), W4-1);
        int pl = (y4c >> 1)*W8 + (x4c >> 1);
        const float* w = U4 + ch*64;
        float s = c3[ch*N4 + y4c*W4 + x4c];
#pragma unroll 8
        for (int ci = 0; ci < 64; ci++) s += c4[ci*N8 + pl] * w[ci];
        u3s[ch*36 + pp] = s;
    }
    __syncthreads();
    for (int i = threadIdx.x; i < 16*100; i += 256) {
        int ch = i / 100, pp = i - ch*100;
        int y2 = hy0 + pp/10, x2 = hx0 + pp%10;
        int y2c = min(max(y2, 0), H2-1), x2c = min(max(x2, 0), W2-1);
        int ly = (y2c >> 1) - qy0, lx = (x2c >> 1) - qx0;
        const float* w = U3 + ch*32;
        float s = c2[ch*N2 + y2c*W2 + x2c];
#pragma unroll 8
        for (int ci = 0; ci < 32; ci++) s += u3s[ci*36 + ly*6 + lx] * w[ci];
        u2s[ch*100 + pp] = s;
    }
    __syncthreads();
    for (int i = threadIdx.x; i < 8*NHALO; i += 256) {
        int ch = i / NHALO, pp = i - ch*NHALO;
        int gy = oy0 + pp/HALO - 1, gx = ox0 + pp%HALO - 1;
        float s = 0.0f;
        if (gy >= 0 && gy < HH && gx >= 0 && gx < WW) {
            int ly = (gy >> 1) - hy0, lx = (gx >> 1) - hx0;
            const float* w = U2 + ch*16;
            s = c1[ch*NP + gy*WW + gx];
#pragma unroll
            for (int ci = 0; ci < 16; ci++) s += u2s[ci*100 + ly*10 + lx] * w[ci];
        }
        u1s[ch*NHALO + pp] = s;
    }
    __syncthreads();
    int px = threadIdx.x & 15, py = threadIdx.x >> 4;
    int base = py*HALO + px;
    float cost = 0.0f;
#pragma unroll
    for (int ci = 0; ci < 8; ci++) {
        const float* w = Wout + ci*9;
#pragma unroll
        for (int ky = 0; ky < 3; ky++)
#pragma unroll
            for (int kx = 0; kx < 3; kx++)
                cost += u1s[ci*NHALO + base + ky*HALO + kx] * w[ky*3 + kx];
    }
    int p = (oy0 + py)*WW + ox0 + px;
    float prob = expf(cost);
    exp_sum[p] += prob;
    depth_img[p] += dslice[p] * prob;
    max_prob[p] = fmaxf(max_prob[p], prob);
}

// ================= uber kernel: one diagonal of the pipeline =================
__global__ __launch_bounds__(256) void k_uber(
        int t,
        const float* __restrict__ feats, const float* __restrict__ rel,
        const float* __restrict__ depthv,
        const float* __restrict__ W0, const float* __restrict__ Ws1,
        const float* __restrict__ W1, const float* __restrict__ Ws2,
        const float* __restrict__ W2w, const float* __restrict__ Ws3,
        const float* __restrict__ W3w, const float* __restrict__ Ws4,
        const float* __restrict__ U4, const float* __restrict__ U3,
        const float* __restrict__ U2, const float* __restrict__ Wout,
        float* __restrict__ c1r, float* __restrict__ c2r,
        float* __restrict__ c3r, float* __restrict__ c4r,
        float* __restrict__ esum, float* __restrict__ dimg,
        float* __restrict__ maxp) {
    __shared__ float smem[SMEM_FLOATS];   // 21376 B -> 7 blocks/CU
    int b = blockIdx.x;
    if (b < 400) {
        int d = t;
        if (d < DD) stageA(b, d, feats, rel, depthv, c1r, W0, Ws1, smem);
    } else if (b < 800) {
        int d = t - 1;
        if (d >= 0 && d < DD) stageB(b - 400, d, c1r, c2r, W1, Ws2);
    } else if (b < 1000) {
        int d = t - 2;
        if (d >= 0 && d < DD) stageC(b - 800, d, c2r, c3r, W2w, Ws3);
    } else if (b < 1112) {
        int d = t - 3;
        if (d >= 0 && d < DD) stageD(b - 1000, d, c3r, c4r, W3w, Ws4);
    } else {
        int d = t - 4;
        if (d >= 0 && d < DD)
            stageU(b - 1112, d, c1r, c2r, c3r, c4r, U4, U3, U2, Wout, depthv,
                   esum, dimg, maxp, smem);
    }
}

// ---------------- final normalize ----------------
__global__ __launch_bounds__(256) void k_final(
        const float* __restrict__ exp_sum, const float* __restrict__ depth_img,
        const float* __restrict__ max_prob, float* __restrict__ out) {
    int p = blockIdx.x*256 + threadIdx.x;
    if (p >= NP) return;
    float es = exp_sum[p] + 1e-10f;
    out[p] = depth_img[p] / es;
    out[NP + p] = max_prob[p] / es;
}

extern "C" void kernel_launch(void* const* d_in, const int* in_sizes, int n_in,
                              void* d_out, int out_size, void* d_ws, size_t ws_size,
                              hipStream_t stream) {
    const float* feats = (const float*)d_in[0];
    const float* proj  = (const float*)d_in[1];
    const float* depthv= (const float*)d_in[2];
    const float* W0  = (const float*)d_in[3];
    const float* Ws1 = (const float*)d_in[4];
    const float* W1  = (const float*)d_in[5];
    const float* Ws2 = (const float*)d_in[6];
    const float* W2w = (const float*)d_in[7];
    const float* Ws3 = (const float*)d_in[8];
    const float* W3w = (const float*)d_in[9];
    const float* Ws4 = (const float*)d_in[10];
    const float* U4  = (const float*)d_in[11];
    const float* U3  = (const float*)d_in[12];
    const float* U2  = (const float*)d_in[13];
    const float* Wout= (const float*)d_in[14];

    float* ws = (float*)d_ws;
    float* rel  = ws + OFF_REL;
    float* c1r  = ws + OFF_C1R;
    float* c2r  = ws + OFF_C2R;
    float* c3r  = ws + OFF_C3R;
    float* c4r  = ws + OFF_C4R;
    float* esum = ws + OFF_ESUM;
    float* dimg = ws + OFF_DIMG;
    float* maxp = ws + OFF_MAXP;

    // zero all rings + accumulators; ring slots double as the zero "previous
    // skip" inputs for d=0.
    hipMemsetAsync(c1r, 0, (size_t)(OFF_END - OFF_C1R) * sizeof(float), stream);
    k_prep<<<1, 1, 0, stream>>>(proj, rel);

    for (int t = 0; t < DD + 4; t++) {
        k_uber<<<dim3(1512), 256, 0, stream>>>(t, feats, rel, depthv,
            W0, Ws1, W1, Ws2, W2w, Ws3, W3w, Ws4, U4, U3, U2, Wout,
            c1r, c2r, c3r, c4r, esum, dimg, maxp);
    }
    k_final<<<dim3(400), 256, 0, stream>>>(esum, dimg, maxp, (float*)d_out);
}